// Round 11
// baseline (1546.620 us; speedup 1.0000x reference)
//
#include <hip/hip_runtime.h>
#include <hip/hip_bf16.h>
#include <math.h>

// Problem constants (match reference)
#define T_TOK 1024
#define HID   2048
#define NEXP  64
#define IDIM  1024
#define ISH   2048      // IS = I * N_SHARED
#define TOPK  8

typedef float  f32x4  __attribute__((ext_vector_type(4)));
typedef __bf16 bf16x8 __attribute__((ext_vector_type(8)));

#define BM  128

// Barrier that does NOT drain vmcnt (waits own DS ops only).
#define BARRIER_NODRAIN() asm volatile("s_waitcnt lgkmcnt(0)\n\ts_barrier" ::: "memory")

__device__ __forceinline__ bf16x8 cvt8(f32x4 a, f32x4 b) {
  bf16x8 v;
  v[0]=(__bf16)a[0]; v[1]=(__bf16)a[1]; v[2]=(__bf16)a[2]; v[3]=(__bf16)a[3];
  v[4]=(__bf16)b[0]; v[5]=(__bf16)b[1]; v[6]=(__bf16)b[2]; v[7]=(__bf16)b[3];
  return v;
}

// ---------------- init: zero expert counts ----------------
__global__ void init_kernel(int* counts) {
  if (threadIdx.x < NEXP) counts[threadIdx.x] = 0;
}

// ---------------- x (f32) -> x_bf16 ----------------
__global__ void xcast_kernel(const float* __restrict__ x, __bf16* __restrict__ xb) {
  long i = ((long)blockIdx.x * 256 + threadIdx.x) * 8;
  f32x4 a = *(const f32x4*)(x + i);
  f32x4 b = *(const f32x4*)(x + i + 4);
  *(bf16x8*)(xb + i) = cvt8(a, b);
}

// ---------------- router: logits + sigmoid + grouped top-k (f32) ----------------
__global__ __launch_bounds__(256)
void router_kernel(const float* __restrict__ x, const float* __restrict__ gw,
                   const float* __restrict__ eb,
                   int* __restrict__ ids, float* __restrict__ wts,
                   int* __restrict__ counts)
{
  __shared__ __align__(16) float xs[HID];
  __shared__ float red[256];
  __shared__ float sc[NEXP], sb[NEXP];
  const int t = blockIdx.x, tid = threadIdx.x;

  const f32x4* xsrc = (const f32x4*)(x + (long)t * HID);
  f32x4* xd = (f32x4*)xs;
  xd[tid]       = xsrc[tid];
  xd[tid + 256] = xsrc[tid + 256];
  __syncthreads();

  const int e = tid & 63, part = tid >> 6;
  const f32x4* wrow = (const f32x4*)(gw + (long)e * HID + part * 512);
  const f32x4* xrow = (const f32x4*)(xs + part * 512);
  float s = 0.f;
  #pragma unroll 4
  for (int j = 0; j < 128; ++j) {
    f32x4 wv = wrow[j], xv = xrow[j];
    s += wv[0]*xv[0] + wv[1]*xv[1] + wv[2]*xv[2] + wv[3]*xv[3];
  }
  red[tid] = s;
  __syncthreads();
  if (part == 0) {
    float logit = red[e] + red[e+64] + red[e+128] + red[e+192];
    float sig = 1.f / (1.f + expf(-logit));   // accurate exp: selection must match f32 ref
    sc[e] = sig; sb[e] = sig + eb[e];
  }
  __syncthreads();

  if (tid == 0) {
    float gsc[8];
    for (int g = 0; g < 8; ++g) {
      float m1 = -1e30f, m2 = -1e30f;
      for (int j = 0; j < 8; ++j) {
        float v = sb[g*8 + j];
        if (v > m1) { m2 = m1; m1 = v; } else if (v > m2) m2 = v;
      }
      gsc[g] = m1 + m2;
    }
    unsigned gmask = 0;
    for (int it = 0; it < 4; ++it) {
      int best = 0; float bv = -1e30f;
      for (int g = 0; g < 8; ++g)
        if (!((gmask >> g) & 1) && gsc[g] > bv) { bv = gsc[g]; best = g; }
      gmask |= 1u << best;
    }
    unsigned long long taken = 0;
    int id8[8]; float wsum = 0.f;
    for (int it = 0; it < 8; ++it) {
      int best = 0; float bv = -1e30f;
      for (int e2 = 0; e2 < 64; ++e2) {
        if (!((gmask >> (e2 >> 3)) & 1)) continue;
        if ((taken >> e2) & 1) continue;
        float v = sb[e2];
        if (v > bv) { bv = v; best = e2; }
      }
      taken |= 1ull << best;
      id8[it] = best; wsum += sc[best];
    }
    float inv = 2.5f / wsum;   // fold ROUTED_SCALE into weights
    for (int k = 0; k < 8; ++k) {
      ids[t*8 + k] = id8[k];
      wts[t*8 + k] = sc[id8[k]] * inv;
      atomicAdd(&counts[id8[k]], 1);
    }
  }
}

// ---------------- prefix scan + (expert, mt) pair worklist (BM=128 chunks) ----
__global__ void scan_kernel(const int* __restrict__ counts,
                            int* __restrict__ seg_off, int* __restrict__ cursors,
                            int* __restrict__ pair_e, int* __restrict__ pair_mt,
                            int* __restrict__ npairs) {
  if (threadIdx.x == 0) {
    int off = 0, np = 0;
    for (int e = 0; e < NEXP; ++e) {
      seg_off[e] = off; cursors[e] = off;
      int c = counts[e]; off += c;
      for (int m = 0; m * BM < c; ++m) { pair_e[np] = e; pair_mt[np] = m; ++np; }
    }
    npairs[0] = np;
  }
}

// ---------------- scatter (t, w) into per-expert segments ----------------
__global__ void scatter_kernel(const int* __restrict__ ids, const float* __restrict__ wts,
                               int* __restrict__ cursors,
                               int* __restrict__ tok_list, float* __restrict__ wgt_list,
                               int* __restrict__ pos_of) {
  int idx = blockIdx.x * 256 + threadIdx.x;
  if (idx >= T_TOK * TOPK) return;
  int t = idx >> 3;
  int e = ids[idx];
  int pos = atomicAdd(&cursors[e], 1);
  tok_list[pos] = t;
  wgt_list[pos] = wts[idx];
  pos_of[idx] = pos;
}

// ---------------- page-streamed GEMM ----------------
// DRAM-page-friendly B staging: supersteps of SK k-elems; each global_load_lds
// instr reads a 1 KB (BN=32) / 512 B (BN=64) CONTIGUOUS burst of ONE B row.
// B f32 in LDS, 3-deep superstep rotation (3x32 KB); cvt->bf16 at read.
// A (bf16, L2-resident) staged per 32-k step into a 7-deep 8 KB ring.
// Constant bundle (NBI B + 2 A DMA instrs) per inner step on one FIFO ->
// constant counted vmcnt; one no-drain barrier per inner step.
// EPI 0: bf16 C via LDS transpose. EPI 2: f32 direct store.
template<int BN, int SK, int EPI, bool ROUTED, bool GATHER>
__global__ __launch_bounds__(256, 1)
void gemm_ps(const __bf16* __restrict__ A, const float* __restrict__ Bg0,
             const float* __restrict__ Bu0, long strideBe, int ldB, int K,
             void* Cg, void* Cu, int ldc,
             const int* __restrict__ pair_e, const int* __restrict__ pair_mt,
             const int* __restrict__ npairs,
             const int* __restrict__ seg_off, const int* __restrict__ seg_cnt,
             const int* __restrict__ tok_list, int Mfull)
{
  constexpr int INNER = SK / 32;            // inner steps per superstep (8 / 4)
  constexpr int NBI   = 8 / INNER;          // B instrs per wave per step (1 / 2)
  constexpr int MR    = (BN == 32) ? 4 : 8; // m-frags per wave
  constexpr int AH    = (BN == 32) ? 5 : 4; // A stage-ahead
  constexpr int CNT   = AH * (NBI + 2);     // constant vmcnt (15 / 16)
  constexpr int RPI   = (BN == 32) ? 1 : 2; // B rows per instr
  constexpr int CH    = 1024 / RPI;         // bytes per row per superstep
  constexpr int CM    = CH / 16 - 1;        // chunk swizzle mask

  __shared__ __align__(16) char sB[3][BN * CH];   // 3 x 32 KB
  __shared__ __align__(16) char sA[7][8192];      // 7 x 8 KB

  const int tid = threadIdx.x, lane = tid & 63, wv = tid >> 6;
  const int c15 = lane & 15, hi = lane >> 4;
  const int colg = (BN == 32) ? (wv >> 1) * 16 : wv * 16;
  const int row0 = (BN == 32) ? (wv & 1) * 64 : 0;

  int e, mt0, soff, cnt;
  if (ROUTED) {
    int p = blockIdx.y;
    if (p >= npairs[0]) return;
    e = pair_e[p]; mt0 = pair_mt[p]; soff = seg_off[e]; cnt = seg_cnt[e];
  } else {
    e = 0; mt0 = blockIdx.y; soff = 0; cnt = Mfull;
  }
  const int rem = cnt - mt0 * BM;
  if (rem <= 0) return;

  const float* B0 = (gridDim.z == 2 && blockIdx.z) ? Bu0 : Bg0;
  void* Cout      = (gridDim.z == 2 && blockIdx.z) ? Cu  : Cg;
  const float* Bb = B0 + (long)e * strideBe + (long)(blockIdx.x * BN) * ldB;

  // A staging sources: 2 instrs/wave/step; instr i covers rows (wv*2+i)*16..+15,
  // 64 B per row per step; source chunk pre-XOR'd so LDS stays linear.
  const __bf16* srcA[2];
  #pragma unroll
  for (int i = 0; i < 2; ++i) {
    int row = (wv * 2 + i) * 16 + (lane >> 2);
    int kc  = (lane & 3) ^ (row & 3);
    int rr  = (row < rem) ? row : (rem - 1);
    int idx = soff + mt0 * BM + rr;
    long arow = GATHER ? (long)tok_list[idx] : (long)idx;
    srcA[i] = A + arow * (long)K + kc * 8;
  }

#define ISSUE_B(q, bd, ssk) { \
  int r0_ = (BN == 32) ? (wv * 8 + (q)) : (wv * 16 + (q) * 2); \
  int row_ = r0_ + ((RPI == 2) ? (lane >> 5) : 0); \
  int chunk_ = ((RPI == 2) ? (lane & 31) : lane) ^ (row_ & CM); \
  const float* src_ = Bb + (long)row_ * ldB + (ssk) + chunk_ * 4; \
  __builtin_amdgcn_global_load_lds((const __attribute__((address_space(1))) void*)src_, \
      (__attribute__((address_space(3))) void*)(&sB[bd][r0_ * CH]), 16, 0, 0); }

#define ISSUE_A(ta, NTt_) { \
  int ad_ = (ta) % 7; \
  int ka_ = (((ta) < (NTt_)) ? (ta) : ((NTt_) - 1)) * 32; \
  _Pragma("unroll") \
  for (int i = 0; i < 2; ++i) \
    __builtin_amdgcn_global_load_lds((const __attribute__((address_space(1))) void*)(srcA[i] + ka_), \
        (__attribute__((address_space(3))) void*)(&sA[ad_][(wv * 2 + i) * 1024]), 16, 0, 0); }

  f32x4 acc[MR] = {};

#define COMPUTE(ab, bb, tl) { \
  const char* Bl_ = sB[bb]; \
  const int col_ = colg + c15; \
  const int c0_ = (tl) * 8 + hi * 2; \
  f32x4 b0_ = *(const f32x4*)(Bl_ + col_ * CH + (((c0_    ) ^ (col_ & CM)) << 4)); \
  f32x4 b1_ = *(const f32x4*)(Bl_ + col_ * CH + (((c0_ + 1) ^ (col_ & CM)) << 4)); \
  bf16x8 bf_ = cvt8(b0_, b1_); \
  const char* Al_ = sA[ab]; \
  _Pragma("unroll") \
  for (int m = 0; m < MR; ++m) { \
    int row_ = row0 + m * 16 + c15; \
    bf16x8 af_ = *(const bf16x8*)(Al_ + row_ * 64 + ((hi ^ (row_ & 3)) << 4)); \
    acc[m] = __builtin_amdgcn_mfma_f32_16x16x32_bf16(af_, bf_, acc[m], 0, 0, 0); \
  } }

  const int NSS = K / SK;
  const int NTt = NSS * INNER;

  // prologue: B(0), A(0..AH-1), B(1)
  #pragma unroll
  for (int q = 0; q < 8; ++q) ISSUE_B(q, 0, 0);
  for (int j = 0; j < AH; ++j) ISSUE_A(j, NTt);
  #pragma unroll
  for (int q = 0; q < 8; ++q) ISSUE_B(q, 1, SK);

  for (int t = 0; t < NTt; ++t) {
    // bundle: B rows for superstep pss (delayed by 1 step; t=0 dup of p=0)
    int pB  = (t > 0) ? (t - 1) : 0;
    int pss = pB / INNER + 2;
    int bd  = pss % 3;
    int ssk = (((pss < NSS) ? pss : (NSS - 1))) * SK;
    int qb  = (pB % INNER) * NBI;
    ISSUE_B(qb, bd, ssk);
    if (NBI == 2) ISSUE_B(qb + 1, bd, ssk);
    ISSUE_A(t + AH, NTt);
    asm volatile("s_waitcnt vmcnt(%0)" :: "i"(CNT) : "memory");
    BARRIER_NODRAIN();
    COMPUTE(t % 7, (t / INNER) % 3, t % INNER);
  }
#undef ISSUE_B
#undef ISSUE_A
#undef COMPUTE

  asm volatile("s_waitcnt vmcnt(0)" ::: "memory");
  __syncthreads();

  if constexpr (EPI == 0) {
    __bf16* Cs = (__bf16*)&sB[0][0];                 // scratch: 128 x BN bf16
    #pragma unroll
    for (int m = 0; m < MR; ++m) {
      #pragma unroll
      for (int r = 0; r < 4; ++r) {
        int row = row0 + m * 16 + hi * 4 + r;
        Cs[row * BN + colg + c15] = (__bf16)acc[m][r];
      }
    }
    __syncthreads();
    __bf16* Cb = (__bf16*)Cout;
    const int row = tid >> 1, half = tid & 1;
    if (row < rem) {
      __bf16* dst = Cb + (long)(soff + mt0 * BM + row) * ldc + blockIdx.x * BN;
      // each of the 2 threads/row stores BN/16 bf16x8 chunks (FIX: was BN/32,
      // which skipped half the columns -> poison in output)
      #pragma unroll
      for (int j = 0; j < BN / 16; ++j) {
        int c8 = half * (BN / 16) + j;
        *(bf16x8*)(dst + c8 * 8) = *(const bf16x8*)&Cs[row * BN + c8 * 8];
      }
    }
  } else {
    float* O = (float*)Cout;
    const int col = blockIdx.x * BN + colg + c15;
    #pragma unroll
    for (int m = 0; m < MR; ++m) {
      #pragma unroll
      for (int r = 0; r < 4; ++r) {
        int row = row0 + m * 16 + hi * 4 + r;
        if (row < rem)
          O[(long)(mt0 * BM + row) * ldc + col] = acc[m][r];
      }
    }
  }
}

// ---------------- fuse: h = silu(g) * u * w  (in place into g) ----------------
__global__ void fuse_kernel(__bf16* __restrict__ g, const __bf16* __restrict__ u,
                            const float* __restrict__ wrow, int rshift) {
  long idx = ((long)blockIdx.x * 256 + threadIdx.x) * 8;
  bf16x8 gv = *(bf16x8*)(g + idx);
  bf16x8 uv = *(const bf16x8*)(u + idx);
  float w = wrow ? wrow[idx >> rshift] : 1.f;
  bf16x8 h;
  #pragma unroll
  for (int j = 0; j < 8; ++j) {
    float gf = (float)gv[j], uf = (float)uv[j];
    h[j] = (__bf16)(w * gf * uf / (1.f + __expf(-gf)));
  }
  *(bf16x8*)(g + idx) = h;
}

// ---------------- combine: out[t] += sum_k y[pos(t,k)] ----------------
__global__ __launch_bounds__(256)
void combine_kernel(const __bf16* __restrict__ y, const int* __restrict__ pos_of,
                    float* __restrict__ out) {
  const int t = blockIdx.x;
  const int c0 = threadIdx.x * 8;
  float* orow = out + (long)t * HID + c0;
  f32x4 s0 = *(const f32x4*)orow;
  f32x4 s1 = *(const f32x4*)(orow + 4);
  #pragma unroll
  for (int k = 0; k < TOPK; ++k) {
    int row = pos_of[t * TOPK + k];
    bf16x8 v = *(const bf16x8*)(y + (long)row * HID + c0);
    s0[0] += (float)v[0]; s0[1] += (float)v[1]; s0[2] += (float)v[2]; s0[3] += (float)v[3];
    s1[0] += (float)v[4]; s1[1] += (float)v[5]; s1[2] += (float)v[6]; s1[3] += (float)v[7];
  }
  *(f32x4*)orow = s0;
  *(f32x4*)(orow + 4) = s1;
}

// ---------------- launch ----------------
extern "C" void kernel_launch(void* const* d_in, const int* in_sizes, int n_in,
                              void* d_out, int out_size, void* d_ws, size_t ws_size,
                              hipStream_t stream) {
  const float* x      = (const float*)d_in[0];
  const float* gate_w = (const float*)d_in[1];
  const float* e_bias = (const float*)d_in[2];
  const float* w_gate = (const float*)d_in[3];
  const float* w_up   = (const float*)d_in[4];
  const float* w_down = (const float*)d_in[5];
  const float* sw_gu  = (const float*)d_in[6];
  const float* sw_d   = (const float*)d_in[7];
  float* out = (float*)d_out;
  char* ws = (char*)d_ws;

  size_t off = 0;
  __bf16* x_bf = (__bf16*)(ws + off);        off += (size_t)T_TOK * HID * 2;   // 4 MB
  int*    ids  = (int*)(ws + off);           off += T_TOK * TOPK * 4;
  float*  wts  = (float*)(ws + off);         off += T_TOK * TOPK * 4;
  int* counts  = (int*)(ws + off);           off += 256;
  int* segoff  = (int*)(ws + off);           off += 256;
  int* cursors = (int*)(ws + off);           off += 256;
  int* pair_e  = (int*)(ws + off);           off += 1024;
  int* pair_mt = (int*)(ws + off);           off += 1024;
  int* npairs  = (int*)(ws + off);           off += 256;
  int* tok_list = (int*)(ws + off);          off += T_TOK * TOPK * 4;
  float* wgt_list = (float*)(ws + off);      off += T_TOK * TOPK * 4;
  int* pos_of  = (int*)(ws + off);           off += T_TOK * TOPK * 4;
  off = (off + 255) & ~(size_t)255;
  __bf16* g_buf  = (__bf16*)(ws + off);      off += (size_t)T_TOK * TOPK * IDIM * 2; // 16 MB
  __bf16* u_buf  = (__bf16*)(ws + off);      off += (size_t)T_TOK * TOPK * IDIM * 2; // 16 MB
  __bf16* gs_buf = (__bf16*)(ws + off);      off += (size_t)T_TOK * ISH * 2;         // 4 MB
  __bf16* us_buf = (__bf16*)(ws + off);      off += (size_t)T_TOK * ISH * 2;         // 4 MB
  __bf16* y_buf  = (__bf16*)(ws + off);      off += (size_t)T_TOK * TOPK * HID * 2;  // 32 MB

  init_kernel<<<1, 64, 0, stream>>>(counts);
  xcast_kernel<<<(T_TOK * HID) / (256 * 8), 256, 0, stream>>>(x, x_bf);
  router_kernel<<<T_TOK, 256, 0, stream>>>(x, gate_w, e_bias, ids, wts, counts);
  scan_kernel<<<1, 64, 0, stream>>>(counts, segoff, cursors, pair_e, pair_mt, npairs);
  scatter_kernel<<<(T_TOK * TOPK + 255) / 256, 256, 0, stream>>>(
      ids, wts, cursors, tok_list, wgt_list, pos_of);

  // routed gate (z=0) + up (z=1): page-streamed B (SK=256 -> 1 KB/row bursts)
  gemm_ps<32, 256, 0, true, true><<<dim3(IDIM / 32, 128, 2), 256, 0, stream>>>(
      x_bf, w_gate, w_up, (long)IDIM * HID, HID, HID, g_buf, u_buf, IDIM,
      pair_e, pair_mt, npairs, segoff, counts, tok_list, 0);

  // h = silu(g)*u*w  (w includes ROUTED_SCALE and renorm)
  fuse_kernel<<<(T_TOK * TOPK * IDIM) / (256 * 8), 256, 0, stream>>>(g_buf, u_buf, wgt_list, 10);

  // shared gate (z=0) + up (z=1)
  gemm_ps<32, 256, 0, false, false><<<dim3(ISH / 32, T_TOK / BM, 2), 256, 0, stream>>>(
      x_bf, sw_gu, sw_gu + (size_t)ISH * HID, 0, HID, HID, gs_buf, us_buf, ISH,
      nullptr, nullptr, nullptr, nullptr, nullptr, nullptr, T_TOK);
  fuse_kernel<<<(T_TOK * ISH) / (256 * 8), 256, 0, stream>>>(gs_buf, us_buf, nullptr, 11);

  // shared down: f32 stores into out (initializes all of d_out). BN=64, SK=128.
  gemm_ps<64, 128, 2, false, false><<<dim3(HID / 64, T_TOK / BM, 1), 256, 0, stream>>>(
      gs_buf, sw_d, sw_d, 0, ISH, ISH, out, out, HID,
      nullptr, nullptr, nullptr, nullptr, nullptr, nullptr, T_TOK);

  // routed down -> y rows (bf16, atomic-free, segment-ordered)
  gemm_ps<64, 128, 0, true, false><<<dim3(HID / 64, 128, 1), 256, 0, stream>>>(
      g_buf, w_down, w_down, (long)HID * IDIM, IDIM, IDIM, y_buf, y_buf, HID,
      pair_e, pair_mt, npairs, segoff, counts, tok_list, 0);

  // combine: out[t] += sum of this token's 8 y rows
  combine_kernel<<<T_TOK, 256, 0, stream>>>(y_buf, pos_of, out);
}

// Round 12
// 650.851 us; speedup vs baseline: 2.3763x; 2.3763x over previous
//
#include <hip/hip_runtime.h>
#include <hip/hip_bf16.h>
#include <math.h>

// Problem constants (match reference)
#define T_TOK 1024
#define HID   2048
#define NEXP  64
#define IDIM  1024
#define ISH   2048      // IS = I * N_SHARED
#define TOPK  8

typedef float  f32x4  __attribute__((ext_vector_type(4)));
typedef __bf16 bf16x8 __attribute__((ext_vector_type(8)));

#define BM  128
#define BN_ 64

__device__ __forceinline__ bf16x8 cvt8(f32x4 a, f32x4 b) {
  bf16x8 v;
  v[0]=(__bf16)a[0]; v[1]=(__bf16)a[1]; v[2]=(__bf16)a[2]; v[3]=(__bf16)a[3];
  v[4]=(__bf16)b[0]; v[5]=(__bf16)b[1]; v[6]=(__bf16)b[2]; v[7]=(__bf16)b[3];
  return v;
}

// ---------------- init: zero expert counts ----------------
__global__ void init_kernel(int* counts) {
  if (threadIdx.x < NEXP) counts[threadIdx.x] = 0;
}

// ---------------- x (f32) -> x_bf16 ----------------
__global__ void xcast_kernel(const float* __restrict__ x, __bf16* __restrict__ xb) {
  long i = ((long)blockIdx.x * 256 + threadIdx.x) * 8;
  f32x4 a = *(const f32x4*)(x + i);
  f32x4 b = *(const f32x4*)(x + i + 4);
  *(bf16x8*)(xb + i) = cvt8(a, b);
}

// ---------------- router: logits + sigmoid + grouped top-k (f32) ----------------
__global__ __launch_bounds__(256)
void router_kernel(const float* __restrict__ x, const float* __restrict__ gw,
                   const float* __restrict__ eb,
                   int* __restrict__ ids, float* __restrict__ wts,
                   int* __restrict__ counts)
{
  __shared__ __align__(16) float xs[HID];
  __shared__ float red[256];
  __shared__ float sc[NEXP], sb[NEXP];
  const int t = blockIdx.x, tid = threadIdx.x;

  const f32x4* xsrc = (const f32x4*)(x + (long)t * HID);
  f32x4* xd = (f32x4*)xs;
  xd[tid]       = xsrc[tid];
  xd[tid + 256] = xsrc[tid + 256];
  __syncthreads();

  const int e = tid & 63, part = tid >> 6;
  const f32x4* wrow = (const f32x4*)(gw + (long)e * HID + part * 512);
  const f32x4* xrow = (const f32x4*)(xs + part * 512);
  float s = 0.f;
  #pragma unroll 4
  for (int j = 0; j < 128; ++j) {
    f32x4 wv = wrow[j], xv = xrow[j];
    s += wv[0]*xv[0] + wv[1]*xv[1] + wv[2]*xv[2] + wv[3]*xv[3];
  }
  red[tid] = s;
  __syncthreads();
  if (part == 0) {
    float logit = red[e] + red[e+64] + red[e+128] + red[e+192];
    float sig = 1.f / (1.f + expf(-logit));   // accurate exp: selection must match f32 ref
    sc[e] = sig; sb[e] = sig + eb[e];
  }
  __syncthreads();

  if (tid == 0) {
    float gsc[8];
    for (int g = 0; g < 8; ++g) {
      float m1 = -1e30f, m2 = -1e30f;
      for (int j = 0; j < 8; ++j) {
        float v = sb[g*8 + j];
        if (v > m1) { m2 = m1; m1 = v; } else if (v > m2) m2 = v;
      }
      gsc[g] = m1 + m2;
    }
    unsigned gmask = 0;
    for (int it = 0; it < 4; ++it) {
      int best = 0; float bv = -1e30f;
      for (int g = 0; g < 8; ++g)
        if (!((gmask >> g) & 1) && gsc[g] > bv) { bv = gsc[g]; best = g; }
      gmask |= 1u << best;
    }
    unsigned long long taken = 0;
    int id8[8]; float wsum = 0.f;
    for (int it = 0; it < 8; ++it) {
      int best = 0; float bv = -1e30f;
      for (int e2 = 0; e2 < 64; ++e2) {
        if (!((gmask >> (e2 >> 3)) & 1)) continue;
        if ((taken >> e2) & 1) continue;
        float v = sb[e2];
        if (v > bv) { bv = v; best = e2; }
      }
      taken |= 1ull << best;
      id8[it] = best; wsum += sc[best];
    }
    float inv = 2.5f / wsum;   // fold ROUTED_SCALE into weights
    for (int k = 0; k < 8; ++k) {
      ids[t*8 + k] = id8[k];
      wts[t*8 + k] = sc[id8[k]] * inv;
      atomicAdd(&counts[id8[k]], 1);
    }
  }
}

// ---------------- prefix scan + (expert, mt) pair worklist (BM=128 chunks) ----
__global__ void scan_kernel(const int* __restrict__ counts,
                            int* __restrict__ seg_off, int* __restrict__ cursors,
                            int* __restrict__ pair_e, int* __restrict__ pair_mt,
                            int* __restrict__ npairs) {
  if (threadIdx.x == 0) {
    int off = 0, np = 0;
    for (int e = 0; e < NEXP; ++e) {
      seg_off[e] = off; cursors[e] = off;
      int c = counts[e]; off += c;
      for (int m = 0; m * BM < c; ++m) { pair_e[np] = e; pair_mt[np] = m; ++np; }
    }
    npairs[0] = np;
  }
}

// ---------------- scatter (t, w) into per-expert segments ----------------
__global__ void scatter_kernel(const int* __restrict__ ids, const float* __restrict__ wts,
                               int* __restrict__ cursors,
                               int* __restrict__ tok_list, float* __restrict__ wgt_list,
                               int* __restrict__ pos_of) {
  int idx = blockIdx.x * 256 + threadIdx.x;
  if (idx >= T_TOK * TOPK) return;
  int t = idx >> 3;
  int e = ids[idx];
  int pos = atomicAdd(&cursors[e], 1);
  tok_list[pos] = t;
  wgt_list[pos] = wts[idx];
  pos_of[idx] = pos;
}

// ---------------- wave-autonomous K-split streaming GEMM ----------------
// Tile M=128 x N=64. 4 waves split K: wave w handles k-chunks (4s+w)*32.
// Each wave DMA-stages its PRIVATE A-slice (8KB bf16) + B-slice (8KB f32)
// into a private 2x16KB LDS double buffer via global_load_lds, loops
// {STAGE(s+1); vmcnt(16); COMPUTE(s)} with NO barrier -> 4 independent
// DMA streams per CU. Full 128x64 f32 accumulator per wave; cross-wave
// LDS reduce + store at the end. EPI 0: bf16 C store. EPI 2: f32 store.
template<int EPI, bool ROUTED, bool GATHER>
__global__ __launch_bounds__(256, 1)
void gemm_ks(const __bf16* __restrict__ A, const float* __restrict__ Bg0,
             const float* __restrict__ Bu0, long strideBe, int ldB, int K,
             void* Cg, void* Cu, int ldc,
             const int* __restrict__ pair_e, const int* __restrict__ pair_mt,
             const int* __restrict__ npairs,
             const int* __restrict__ seg_off, const int* __restrict__ seg_cnt,
             const int* __restrict__ tok_list, int Mfull)
{
  __shared__ __align__(16) char smem[4 * 32768];   // 128 KB: 32 KB per wave
  const int tid = threadIdx.x, lane = tid & 63, wv = tid >> 6;
  const int c15 = lane & 15, hi = lane >> 4;

  int e, mt0, soff, cnt;
  if (ROUTED) {
    int p = blockIdx.y;
    if (p >= npairs[0]) return;
    e = pair_e[p]; mt0 = pair_mt[p]; soff = seg_off[e]; cnt = seg_cnt[e];
  } else {
    e = 0; mt0 = blockIdx.y; soff = 0; cnt = Mfull;
  }
  const int rem = cnt - mt0 * BM;
  if (rem <= 0) return;

  const float* B0 = (gridDim.z == 2 && blockIdx.z) ? Bu0 : Bg0;
  void* Cout      = (gridDim.z == 2 && blockIdx.z) ? Cu  : Cg;
  const float* Bb0 = B0 + (long)e * strideBe;

  char* Wb = smem + wv * 32768;   // this wave's private 32 KB

  // staging sources (include wave k-base wv*32; advance by s*128 elems/step)
  const __bf16* srcA[8];
  const float*  srcB[8];
  #pragma unroll
  for (int i = 0; i < 8; ++i) {
    int row = i * 16 + (lane >> 2);
    int kcA = (lane & 3) ^ (row & 3);
    int rr  = (row < rem) ? row : (rem - 1);
    int idx = soff + mt0 * BM + rr;
    long arow = GATHER ? (long)tok_list[idx] : (long)idx;
    srcA[i] = A + arow * (long)K + wv * 32 + kcA * 8;

    int col = i * 8 + (lane >> 3);
    int kcB = (lane & 7) ^ (col & 7);
    srcB[i] = Bb0 + (long)(blockIdx.x * BN_ + col) * ldB + wv * 32 + kcB * 4;
  }

#define STAGE(b, kk) { \
  char* Ad = Wb + (b) * 16384; \
  char* Bd = Ad + 8192; \
  _Pragma("unroll") \
  for (int i = 0; i < 8; ++i) \
    __builtin_amdgcn_global_load_lds((const __attribute__((address_space(1))) void*)(srcA[i] + (kk)), \
        (__attribute__((address_space(3))) void*)(Ad + i * 1024), 16, 0, 0); \
  _Pragma("unroll") \
  for (int i = 0; i < 8; ++i) \
    __builtin_amdgcn_global_load_lds((const __attribute__((address_space(1))) void*)(srcB[i] + (kk)), \
        (__attribute__((address_space(3))) void*)(Bd + i * 1024), 16, 0, 0); }

  f32x4 acc[8][4] = {};

#define COMPUTE(b) { \
  const char* Al = Wb + (b) * 16384; \
  const char* Bl = Al + 8192; \
  bf16x8 bfrag[4]; \
  _Pragma("unroll") \
  for (int n = 0; n < 4; ++n) { \
    int col = n * 16 + c15; \
    f32x4 b0 = *(const f32x4*)(Bl + col * 128 + (((hi * 2    ) ^ (col & 7)) << 4)); \
    f32x4 b1 = *(const f32x4*)(Bl + col * 128 + (((hi * 2 + 1) ^ (col & 7)) << 4)); \
    bfrag[n] = cvt8(b0, b1); \
  } \
  _Pragma("unroll") \
  for (int m = 0; m < 8; ++m) { \
    int row = m * 16 + c15; \
    bf16x8 af = *(const bf16x8*)(Al + row * 64 + ((hi ^ (row & 3)) << 4)); \
    _Pragma("unroll") \
    for (int n = 0; n < 4; ++n) \
      acc[m][n] = __builtin_amdgcn_mfma_f32_16x16x32_bf16(af, bfrag[n], acc[m][n], 0, 0, 0); \
  } }

  const int S = K / 128;           // own-steps per wave (16 or 8)
  STAGE(0, 0);
  for (int s = 0; s < S; ++s) {
    if (s + 1 < S) {
      STAGE((s + 1) & 1, (s + 1) * 128);
      asm volatile("s_waitcnt vmcnt(16)" ::: "memory");  // stage(s) landed; s+1 in flight
    } else {
      asm volatile("s_waitcnt vmcnt(0)" ::: "memory");
    }
    COMPUTE(s & 1);
  }
#undef STAGE
#undef COMPUTE

  // ---- cross-wave reduction: each wave writes its 128x64 f32 partial ----
  float* Pw = (float*)Wb;
  #pragma unroll
  for (int m = 0; m < 8; ++m)
    #pragma unroll
    for (int n = 0; n < 4; ++n)
      #pragma unroll
      for (int r = 0; r < 4; ++r)
        Pw[(m * 16 + hi * 4 + r) * 64 + n * 16 + c15] = acc[m][n][r];
  __syncthreads();

  const f32x4* P0 = (const f32x4*)(smem);
  const f32x4* P1 = (const f32x4*)(smem + 32768);
  const f32x4* P2 = (const f32x4*)(smem + 65536);
  const f32x4* P3 = (const f32x4*)(smem + 98304);
  #pragma unroll
  for (int j = 0; j < 4; ++j) {
    int a = j * 2048 + tid * 8;            // f32 index into 128x64 tile
    int q = a >> 2;
    f32x4 v0 = P0[q]     + P1[q]     + P2[q]     + P3[q];
    f32x4 v1 = P0[q + 1] + P1[q + 1] + P2[q + 1] + P3[q + 1];
    int row = a >> 6, col = a & 63;
    if (row < rem) {
      if (EPI == 0) {
        __bf16* Cb = (__bf16*)Cout;
        *(bf16x8*)(Cb + (long)(soff + mt0 * BM + row) * ldc + blockIdx.x * BN_ + col) = cvt8(v0, v1);
      } else {
        float* O = (float*)Cout;
        float* dst = O + (long)(mt0 * BM + row) * ldc + blockIdx.x * BN_ + col;
        *(f32x4*)dst = v0;
        *(f32x4*)(dst + 4) = v1;
      }
    }
  }
}

// ---------------- fuse: h = silu(g) * u * w  (in place into g) ----------------
__global__ void fuse_kernel(__bf16* __restrict__ g, const __bf16* __restrict__ u,
                            const float* __restrict__ wrow, int rshift) {
  long idx = ((long)blockIdx.x * 256 + threadIdx.x) * 8;
  bf16x8 gv = *(bf16x8*)(g + idx);
  bf16x8 uv = *(const bf16x8*)(u + idx);
  float w = wrow ? wrow[idx >> rshift] : 1.f;
  bf16x8 h;
  #pragma unroll
  for (int j = 0; j < 8; ++j) {
    float gf = (float)gv[j], uf = (float)uv[j];
    h[j] = (__bf16)(w * gf * uf / (1.f + __expf(-gf)));
  }
  *(bf16x8*)(g + idx) = h;
}

// ---------------- combine: out[t] += sum_k y[pos(t,k)] ----------------
__global__ __launch_bounds__(256)
void combine_kernel(const __bf16* __restrict__ y, const int* __restrict__ pos_of,
                    float* __restrict__ out) {
  const int t = blockIdx.x;
  const int c0 = threadIdx.x * 8;
  float* orow = out + (long)t * HID + c0;
  f32x4 s0 = *(const f32x4*)orow;
  f32x4 s1 = *(const f32x4*)(orow + 4);
  #pragma unroll
  for (int k = 0; k < TOPK; ++k) {
    int row = pos_of[t * TOPK + k];
    bf16x8 v = *(const bf16x8*)(y + (long)row * HID + c0);
    s0[0] += (float)v[0]; s0[1] += (float)v[1]; s0[2] += (float)v[2]; s0[3] += (float)v[3];
    s1[0] += (float)v[4]; s1[1] += (float)v[5]; s1[2] += (float)v[6]; s1[3] += (float)v[7];
  }
  *(f32x4*)orow = s0;
  *(f32x4*)(orow + 4) = s1;
}

// ---------------- launch ----------------
extern "C" void kernel_launch(void* const* d_in, const int* in_sizes, int n_in,
                              void* d_out, int out_size, void* d_ws, size_t ws_size,
                              hipStream_t stream) {
  const float* x      = (const float*)d_in[0];
  const float* gate_w = (const float*)d_in[1];
  const float* e_bias = (const float*)d_in[2];
  const float* w_gate = (const float*)d_in[3];
  const float* w_up   = (const float*)d_in[4];
  const float* w_down = (const float*)d_in[5];
  const float* sw_gu  = (const float*)d_in[6];
  const float* sw_d   = (const float*)d_in[7];
  float* out = (float*)d_out;
  char* ws = (char*)d_ws;

  size_t off = 0;
  __bf16* x_bf = (__bf16*)(ws + off);        off += (size_t)T_TOK * HID * 2;   // 4 MB
  int*    ids  = (int*)(ws + off);           off += T_TOK * TOPK * 4;
  float*  wts  = (float*)(ws + off);         off += T_TOK * TOPK * 4;
  int* counts  = (int*)(ws + off);           off += 256;
  int* segoff  = (int*)(ws + off);           off += 256;
  int* cursors = (int*)(ws + off);           off += 256;
  int* pair_e  = (int*)(ws + off);           off += 1024;
  int* pair_mt = (int*)(ws + off);           off += 1024;
  int* npairs  = (int*)(ws + off);           off += 256;
  int* tok_list = (int*)(ws + off);          off += T_TOK * TOPK * 4;
  float* wgt_list = (float*)(ws + off);      off += T_TOK * TOPK * 4;
  int* pos_of  = (int*)(ws + off);           off += T_TOK * TOPK * 4;
  off = (off + 255) & ~(size_t)255;
  __bf16* g_buf  = (__bf16*)(ws + off);      off += (size_t)T_TOK * TOPK * IDIM * 2; // 16 MB
  __bf16* u_buf  = (__bf16*)(ws + off);      off += (size_t)T_TOK * TOPK * IDIM * 2; // 16 MB
  __bf16* gs_buf = (__bf16*)(ws + off);      off += (size_t)T_TOK * ISH * 2;         // 4 MB
  __bf16* us_buf = (__bf16*)(ws + off);      off += (size_t)T_TOK * ISH * 2;         // 4 MB
  __bf16* y_buf  = (__bf16*)(ws + off);      off += (size_t)T_TOK * TOPK * HID * 2;  // 32 MB

  init_kernel<<<1, 64, 0, stream>>>(counts);
  xcast_kernel<<<(T_TOK * HID) / (256 * 8), 256, 0, stream>>>(x, x_bf);
  router_kernel<<<T_TOK, 256, 0, stream>>>(x, gate_w, e_bias, ids, wts, counts);
  scan_kernel<<<1, 64, 0, stream>>>(counts, segoff, cursors, pair_e, pair_mt, npairs);
  scatter_kernel<<<(T_TOK * TOPK + 255) / 256, 256, 0, stream>>>(
      ids, wts, cursors, tok_list, wgt_list, pos_of);

  // routed gate (z=0) + up (z=1): A gathered via tok_list
  gemm_ks<0, true, true><<<dim3(IDIM / BN_, 128, 2), 256, 0, stream>>>(
      x_bf, w_gate, w_up, (long)IDIM * HID, HID, HID, g_buf, u_buf, IDIM,
      pair_e, pair_mt, npairs, segoff, counts, tok_list, 0);

  // h = silu(g)*u*w  (w includes ROUTED_SCALE and renorm)
  fuse_kernel<<<(T_TOK * TOPK * IDIM) / (256 * 8), 256, 0, stream>>>(g_buf, u_buf, wgt_list, 10);

  // shared gate (z=0) + up (z=1)
  gemm_ks<0, false, false><<<dim3(ISH / BN_, T_TOK / BM, 2), 256, 0, stream>>>(
      x_bf, sw_gu, sw_gu + (size_t)ISH * HID, 0, HID, HID, gs_buf, us_buf, ISH,
      nullptr, nullptr, nullptr, nullptr, nullptr, nullptr, T_TOK);
  fuse_kernel<<<(T_TOK * ISH) / (256 * 8), 256, 0, stream>>>(gs_buf, us_buf, nullptr, 11);

  // shared down: f32 stores into out (initializes all of d_out)
  gemm_ks<2, false, false><<<dim3(HID / BN_, T_TOK / BM, 1), 256, 0, stream>>>(
      gs_buf, sw_d, sw_d, 0, ISH, ISH, out, out, HID,
      nullptr, nullptr, nullptr, nullptr, nullptr, nullptr, T_TOK);

  // routed down -> y rows (bf16, atomic-free, segment-ordered; weight already in h)
  gemm_ks<0, true, false><<<dim3(HID / BN_, 128, 1), 256, 0, stream>>>(
      g_buf, w_down, w_down, (long)HID * IDIM, IDIM, IDIM, y_buf, y_buf, HID,
      pair_e, pair_mt, npairs, segoff, counts, tok_list, 0);

  // combine: out[t] += sum of this token's 8 y rows
  combine_kernel<<<T_TOK, 256, 0, stream>>>(y_buf, pos_of, out);
}